// Round 7
// baseline (304.879 us; speedup 1.0000x reference)
//
#include <hip/hip_runtime.h>
#include <cstdint>
#include <cstddef>

// Problem constants (MaskedCrossAttention_27986006901343)
#define BB    4
#define TQ    2048
#define DIM   1024
#define TKV   16
#define NLAT  64
#define DLAT  1024
#define HEADS 8
#define DHEAD 64
#define LN_EPS 1e-5f
#define NKV   (TKV*NLAT)      // 1024 latents per batch
#define HD    (HEADS*DHEAD)   // 512

typedef unsigned short u16;
typedef __bf16 bf16x8 __attribute__((ext_vector_type(8)));
typedef float  f32x4  __attribute__((ext_vector_type(4)));

__device__ __forceinline__ u16 f2bf(float f) {      // RNE f32->bf16
    unsigned u = __builtin_bit_cast(unsigned, f);
    u += 0x7fffu + ((u >> 16) & 1u);
    return (u16)(u >> 16);
}
__device__ __forceinline__ void gl_lds16(const void* g, void* l) {
    __builtin_amdgcn_global_load_lds(
        (const __attribute__((address_space(1))) void*)g,
        (__attribute__((address_space(3))) void*)l, 16, 0, 0);
}

// ===========================================================================
// prep_k: fused qtime + LN(qo)->bf16 + cvt(kvo)->bf16 + 3 weight transposes.
// Also zero-inits the mega-kernel's grid-barrier counter (blk 0).
// ===========================================================================
__device__ __forceinline__ void transpose_dev(const float* __restrict__ W,
                                              u16* __restrict__ Wt,
                                              int K, int N, int n0, int k0,
                                              float (*tile)[33]) {
    int t = threadIdx.x;
    int r = t >> 3, c4 = (t & 7) * 4;
    float4 v = *(const float4*)&W[(size_t)(k0 + r) * N + n0 + c4];
    tile[r][c4 + 0] = v.x; tile[r][c4 + 1] = v.y;
    tile[r][c4 + 2] = v.z; tile[r][c4 + 3] = v.w;
    __syncthreads();
    uint2 pk;
    pk.x = (unsigned)f2bf(tile[c4 + 0][r]) | ((unsigned)f2bf(tile[c4 + 1][r]) << 16);
    pk.y = (unsigned)f2bf(tile[c4 + 2][r]) | ((unsigned)f2bf(tile[c4 + 3][r]) << 16);
    *(uint2*)&Wt[(size_t)(n0 + r) * K + k0 + c4] = pk;
}

__global__ __launch_bounds__(256) void prep_k(
    const float* __restrict__ qo, const float* __restrict__ kvo,
    const uint8_t* __restrict__ media,
    const float* __restrict__ ln_g, const float* __restrict__ ln_b,
    const float* __restrict__ Wq, const float* __restrict__ Wkv,
    const float* __restrict__ Wout,
    int* __restrict__ qt, u16* __restrict__ Aq, u16* __restrict__ Akv,
    u16* __restrict__ Wqt, u16* __restrict__ Wkvt, u16* __restrict__ Woutt,
    unsigned* __restrict__ cnt) {
    __shared__ int part[256];
    __shared__ int cnt_sh;
    __shared__ float sh[8];
    __shared__ float mu_s, rs_s;
    __shared__ float tile[32][33];
    int blk = blockIdx.x, t = threadIdx.x;

    if (blk < 4) {                    // ---- qtime (media dtype sniffed) ----
        if (blk == 0 && t == 0) *cnt = 0;   // barrier counter init
        int b = blk;
        int c = 0;
        for (int i = 0; i < 32; ++i) c += (media[t * 32 + i] != 0);
        part[t] = c;
        __syncthreads();
        if (t == 0) { int s = 0; for (int i = 0; i < 256; ++i) s += part[i]; cnt_sh = s; }
        __syncthreads();
        bool is_u8 = (cnt_sh >= 48);
        int vals[8];
        for (int i = 0; i < 8; ++i) {
            int idx = t * 8 + i;
            int m;
            if (is_u8) m = (media[(size_t)b * TQ + idx] != 0) ? 1 : 0;
            else       m = (((const uint32_t*)media)[(size_t)b * TQ + idx] != 0u) ? 1 : 0;
            vals[i] = m;
        }
        int loc = 0;
        for (int i = 0; i < 8; ++i) loc += vals[i];
        __syncthreads();
        part[t] = loc;
        __syncthreads();
        int pre = 0;
        for (int i = 0; i < t; ++i) pre += part[i];
        int run = pre;
        for (int i = 0; i < 8; ++i) {
            run += vals[i];
            qt[(size_t)b * TQ + t * 8 + i] = run;
        }
    } else if (blk < 4 + BB * TQ) {   // ---- LayerNorm + bf16 ----
        int row = blk - 4;
        float4 v = *(const float4*)(qo + (size_t)row * DIM + t * 4);
        float s  = v.x + v.y + v.z + v.w;
        float ss = v.x * v.x + v.y * v.y + v.z * v.z + v.w * v.w;
        for (int off = 32; off; off >>= 1) { s += __shfl_down(s, off); ss += __shfl_down(ss, off); }
        if ((t & 63) == 0) { sh[(t >> 6) * 2] = s; sh[(t >> 6) * 2 + 1] = ss; }
        __syncthreads();
        if (t == 0) {
            float S  = sh[0] + sh[2] + sh[4] + sh[6];
            float SS = sh[1] + sh[3] + sh[5] + sh[7];
            float m  = S * (1.0f / DIM);
            mu_s = m;
            rs_s = rsqrtf(SS * (1.0f / DIM) - m * m + LN_EPS);
        }
        __syncthreads();
        float mu = mu_s, rs = rs_s;
        float4 gv = *(const float4*)(ln_g + t * 4);
        float4 bv = *(const float4*)(ln_b + t * 4);
        float a0 = (v.x - mu) * rs * gv.x + bv.x;
        float a1 = (v.y - mu) * rs * gv.y + bv.y;
        float a2 = (v.z - mu) * rs * gv.z + bv.z;
        float a3 = (v.w - mu) * rs * gv.w + bv.w;
        uint2 pk;
        pk.x = (unsigned)f2bf(a0) | ((unsigned)f2bf(a1) << 16);
        pk.y = (unsigned)f2bf(a2) | ((unsigned)f2bf(a3) << 16);
        *(uint2*)(Aq + (size_t)row * DIM + t * 4) = pk;
    } else if (blk < 4 + BB * TQ + 2048) {   // ---- kvo f32->bf16 ----
        size_t i = (size_t)(blk - 4 - BB * TQ) * 256 + t;
        float4 a = ((const float4*)kvo)[i * 2];
        float4 b = ((const float4*)kvo)[i * 2 + 1];
        uint4 pk;
        pk.x = (unsigned)f2bf(a.x) | ((unsigned)f2bf(a.y) << 16);
        pk.y = (unsigned)f2bf(a.z) | ((unsigned)f2bf(a.w) << 16);
        pk.z = (unsigned)f2bf(b.x) | ((unsigned)f2bf(b.y) << 16);
        pk.w = (unsigned)f2bf(b.z) | ((unsigned)f2bf(b.w) << 16);
        ((uint4*)Akv)[i] = pk;
    } else if (blk < 10244 + 512) {   // ---- Wq^T ----
        int id = blk - 10244;
        transpose_dev(Wq, Wqt, DIM, HD, (id & 15) * 32, (id >> 4) * 32, tile);
    } else if (blk < 10756 + 1024) {  // ---- Wkv^T ----
        int id = blk - 10756;
        transpose_dev(Wkv, Wkvt, DLAT, 2 * HD, (id & 31) * 32, (id >> 5) * 32, tile);
    } else {                          // ---- Wout^T ----
        int id = blk - 11780;
        transpose_dev(Wout, Woutt, HD, DIM, (id & 31) * 32, (id >> 5) * 32, tile);
    }
}

// ===========================================================================
// bf16 MFMA GEMM body (R3-proven, best measured): C = A @ Bt^T * outscale.
// 128x128 tile, BK=32, 4 waves, 2-phase double buffer, global_load_lds.
// ===========================================================================
template <typename CT>
__device__ __forceinline__ void gemm_body(const u16* A, const u16* Bt, CT* C,
                                          int M, int N, int K, float outscale,
                                          int bx, int by,
                                          u16* As0, u16* Bs0, u16* As1, u16* Bs1) {
    int t = threadIdx.x;
    int lane = t & 63, w = t >> 6;
    int wr = w >> 1, wc = w & 1;
    int fr = lane & 15, fg = lane >> 4;
    int row0 = by * 128, col0 = bx * 128;

    const u16* Ag = A  + (size_t)(row0 + (t >> 2)) * K + (t & 3) * 8;
    const u16* Bg = Bt + (size_t)(col0 + (t >> 2)) * K + (t & 3) * 8;
    size_t rstr = (size_t)64 * K;

    int aoff = (wr * 64 + fr) * 32 + fg * 8;
    int boff = (wc * 64 + fr) * 32 + fg * 8;

    f32x4 acc[4][4];
#pragma unroll
    for (int mi = 0; mi < 4; ++mi)
#pragma unroll
        for (int ni = 0; ni < 4; ++ni) acc[mi][ni] = (f32x4){0.f, 0.f, 0.f, 0.f};

    auto stage = [&](u16* Asb, u16* Bsb, int k0) {
        char* al = (char*)Asb + w * 1024;
        char* bl = (char*)Bsb + w * 1024;
        gl_lds16(Ag + k0,        al);
        gl_lds16(Ag + k0 + rstr, al + 4096);
        gl_lds16(Bg + k0,        bl);
        gl_lds16(Bg + k0 + rstr, bl + 4096);
    };
    auto compute = [&](const u16* Asb, const u16* Bsb) {
        bf16x8 af[4], bfv[4];
#pragma unroll
        for (int mi = 0; mi < 4; ++mi) af[mi]  = *(const bf16x8*)(Asb + aoff + mi * 512);
#pragma unroll
        for (int ni = 0; ni < 4; ++ni) bfv[ni] = *(const bf16x8*)(Bsb + boff + ni * 512);
#pragma unroll
        for (int mi = 0; mi < 4; ++mi)
#pragma unroll
            for (int ni = 0; ni < 4; ++ni)
                acc[mi][ni] = __builtin_amdgcn_mfma_f32_16x16x32_bf16(
                    af[mi], bfv[ni], acc[mi][ni], 0, 0, 0);
    };

    int nt = K >> 5;                 // even (16 or 32)
    stage(As0, Bs0, 0);
    __syncthreads();
    for (int it = 0; it < nt; it += 2) {
        stage(As1, Bs1, (it + 1) << 5);
        compute(As0, Bs0);
        __syncthreads();
        if (it + 2 < nt) stage(As0, Bs0, (it + 2) << 5);
        compute(As1, Bs1);
        __syncthreads();
    }

#pragma unroll
    for (int mi = 0; mi < 4; ++mi) {
        int r0 = row0 + wr * 64 + mi * 16 + fg * 4;
#pragma unroll
        for (int ni = 0; ni < 4; ++ni) {
            int c = col0 + wc * 64 + ni * 16 + fr;
#pragma unroll
            for (int j = 0; j < 4; ++j) {
                float val = acc[mi][ni][j] * outscale;
                if constexpr (sizeof(CT) == 2) C[(size_t)(r0 + j) * N + c] = f2bf(val);
                else                           C[(size_t)(r0 + j) * N + c] = val;
            }
        }
    }
}

// ===========================================================================
// attn job (R3-proven body): 16 q-rows x 1 head x 1 batch, MFMA QK^T + PV,
// XOR-swizzled LDS. Arrays passed as pointers (overlaid on GEMM LDS).
// ===========================================================================
__device__ __forceinline__ void attn_job(
    const u16* q, const u16* kv, const int* qt, u16* ao, int job,
    u16* Ks, u16* VT, u16* Ps, float* redm, float* reds) {
    int i0 = (job & 127) * 16;
    int h  = (job >> 7) & 7;
    int b  = job >> 10;
    int t  = threadIdx.x;
    int lane = t & 63, w = t >> 6;
    int fr = lane & 15, fg = lane >> 4;

    int t0 = qt[(size_t)b * TQ + i0];
    if (t0 == 0) {
        int row = t >> 4, c = (t & 15) * 4;
        *(uint2*)&ao[((size_t)(b * TQ + i0 + row)) * HD + h * DHEAD + c] = make_uint2(0, 0);
        return;
    }
    int j0 = (t0 - 1) * 64;

    {   // stage K (swizzled row-major) + V (transposed, swizzled)
        int j = t >> 2, c16 = (t & 3) * 16;
        const u16* kvrow = kv + ((size_t)(b * NKV + j0 + j)) * (2 * HD) + h * DHEAD;
        uint4 k0v = *(const uint4*)(kvrow + c16);
        uint4 k1v = *(const uint4*)(kvrow + c16 + 8);
        uint4 v0v = *(const uint4*)(kvrow + HD + c16);
        uint4 v1v = *(const uint4*)(kvrow + HD + c16 + 8);
        int kb = j * 128 + c16 * 2;
        int swz = (j & 7) << 4;
        *(uint4*)((char*)Ks + ((kb)      ^ swz)) = k0v;
        *(uint4*)((char*)Ks + ((kb + 16) ^ swz)) = k1v;
        const u16* ve0 = (const u16*)&v0v;
        const u16* ve1 = (const u16*)&v1v;
#pragma unroll
        for (int e = 0; e < 8; ++e) {
            int d0 = c16 + e, d1 = c16 + 8 + e;
            *(u16*)((char*)VT + ((d0 * 128 + j * 2) ^ ((d0 & 7) << 4))) = ve0[e];
            *(u16*)((char*)VT + ((d1 * 128 + j * 2) ^ ((d1 & 7) << 4))) = ve1[e];
        }
    }
    const u16* qrow = q + ((size_t)(b * TQ + i0 + fr)) * HD + h * DHEAD + fg * 8;
    bf16x8 aq0 = *(const bf16x8*)(qrow);
    bf16x8 aq1 = *(const bf16x8*)(qrow + 32);
    __syncthreads();

    // QK^T: wave w computes S[16][w*16..w*16+16)
    int r = w * 16 + fr;
    bf16x8 bk0 = *(const bf16x8*)((char*)Ks + ((r * 128 + fg * 16)      ^ ((r & 7) << 4)));
    bf16x8 bk1 = *(const bf16x8*)((char*)Ks + ((r * 128 + 64 + fg * 16) ^ ((r & 7) << 4)));
    f32x4 s = (f32x4){0.f, 0.f, 0.f, 0.f};
    s = __builtin_amdgcn_mfma_f32_16x16x32_bf16(aq0, bk0, s, 0, 0, 0);
    s = __builtin_amdgcn_mfma_f32_16x16x32_bf16(aq1, bk1, s, 0, 0, 0);

    // softmax over 64 cols (4 waves x 16)
#pragma unroll
    for (int j = 0; j < 4; ++j) {
        float m = s[j];
        for (int off = 1; off < 16; off <<= 1) m = fmaxf(m, __shfl_xor(m, off));
        redm[w * 16 + fg * 4 + j] = m;
    }
    __syncthreads();
    float p[4];
#pragma unroll
    for (int j = 0; j < 4; ++j) {
        int row = fg * 4 + j;
        float M = fmaxf(fmaxf(redm[row], redm[16 + row]), fmaxf(redm[32 + row], redm[48 + row]));
        p[j] = __expf(s[j] - M);
        float sm = p[j];
        for (int off = 1; off < 16; off <<= 1) sm += __shfl_xor(sm, off);
        reds[w * 16 + row] = sm;
    }
    __syncthreads();
#pragma unroll
    for (int j = 0; j < 4; ++j) {
        int row = fg * 4 + j;
        float S = reds[row] + reds[16 + row] + reds[32 + row] + reds[48 + row];
        u16 pb = f2bf(p[j] / S);
        *(u16*)((char*)Ps + ((row * 128 + (w * 16 + fr) * 2) ^ ((row & 7) << 4))) = pb;
    }
    __syncthreads();

    // PV: wave w computes O[16][w*16..w*16+16)
    bf16x8 pa0 = *(const bf16x8*)((char*)Ps + ((fr * 128 + fg * 16)      ^ ((fr & 7) << 4)));
    bf16x8 pa1 = *(const bf16x8*)((char*)Ps + ((fr * 128 + 64 + fg * 16) ^ ((fr & 7) << 4)));
    int d = w * 16 + fr;
    bf16x8 bv0 = *(const bf16x8*)((char*)VT + ((d * 128 + fg * 16)      ^ ((d & 7) << 4)));
    bf16x8 bv1 = *(const bf16x8*)((char*)VT + ((d * 128 + 64 + fg * 16) ^ ((d & 7) << 4)));
    f32x4 o = (f32x4){0.f, 0.f, 0.f, 0.f};
    o = __builtin_amdgcn_mfma_f32_16x16x32_bf16(pa0, bv0, o, 0, 0, 0);
    o = __builtin_amdgcn_mfma_f32_16x16x32_bf16(pa1, bv1, o, 0, 0, 0);
#pragma unroll
    for (int j = 0; j < 4; ++j)
        ao[((size_t)(b * TQ + i0 + fg * 4 + j)) * HD + h * DHEAD + d] = f2bf(o[j]);
}

// ===========================================================================
// Device-wide barrier: 512 co-resident blocks (guaranteed: 32KB LDS -> 5/CU
// cap, launch_bounds(256,2) -> >=2/CU, 512 = 2*256CU). Monotonic counter,
// agent-scope acq/rel atomics (cross-XCD safe). Bounded spin (~no-hang).
// ===========================================================================
__device__ __forceinline__ void gridbar(unsigned* cnt, unsigned target) {
    __syncthreads();
    if (threadIdx.x == 0) {
        __hip_atomic_fetch_add(cnt, 1u, __ATOMIC_ACQ_REL, __HIP_MEMORY_SCOPE_AGENT);
        unsigned it = 0;
        while (__hip_atomic_load(cnt, __ATOMIC_ACQUIRE, __HIP_MEMORY_SCOPE_AGENT) < target
               && ++it < 30000000u)
            __builtin_amdgcn_s_sleep(2);
    }
    __syncthreads();
}

// ===========================================================================
// mega_k: proj (512 x 128^2 tiles) -> barrier -> attn (4096 jobs, 8/block)
// -> barrier -> out (512 x 128^2 tiles). One dispatch => visible in top-5
// with counters; removes 2 launch gaps.
// ===========================================================================
__global__ __launch_bounds__(256, 2) void mega_k(
    const u16* Aq,  const u16* Wqt,  u16* qb,
    const u16* Akv, const u16* Wkvt, u16* kvb,
    const int* qt, u16* aob,
    const u16* Woutt, float* out, unsigned* cnt) {
    __shared__ u16 As0[4096], Bs0[4096], As1[4096], Bs1[4096];   // 32KB
    int id = blockIdx.x;

    // ---- phase 1: q-proj + kv-proj ----
    if (id < 256) {
        gemm_body<u16>(Aq, Wqt, qb, BB * TQ, HD, DIM, 0.125f, id & 3, id >> 2,
                       As0, Bs0, As1, Bs1);
    } else {
        int k = id - 256;
        gemm_body<u16>(Akv, Wkvt, kvb, BB * NKV, 2 * HD, DLAT, 1.0f, k & 7, k >> 3,
                       As0, Bs0, As1, Bs1);
    }
    gridbar(cnt, 512);

    // ---- phase 2: attention (8 jobs/block), LDS overlaid on GEMM buffers ----
    {
        u16* Ks = As0;                    // 8KB
        u16* VT = Bs0;                    // 8KB
        u16* Ps = As1;                    // 2KB used
        float* redm = (float*)Bs1;        // 256B
        float* reds = redm + 64;          // 256B
#pragma unroll 1
        for (int jj = 0; jj < 8; ++jj) {
            __syncthreads();
            attn_job(qb, kvb, qt, aob, id * 8 + jj, Ks, VT, Ps, redm, reds);
        }
    }
    gridbar(cnt, 1024);

    // ---- phase 3: out-proj ----
    gemm_body<float>(aob, Woutt, out, BB * TQ, DIM, HD, 1.0f, id & 7, id >> 3,
                     As0, Bs0, As1, Bs1);
}

// ===========================================================================
extern "C" void kernel_launch(void* const* d_in, const int* in_sizes, int n_in,
                              void* d_out, int out_size, void* d_ws, size_t ws_size,
                              hipStream_t stream) {
    const float*   qo    = (const float*)d_in[0];
    const float*   kvo   = (const float*)d_in[1];
    const uint8_t* media = (const uint8_t*)d_in[2];
    const float*   ln_g  = (const float*)d_in[3];
    const float*   ln_b  = (const float*)d_in[4];
    const float*   Wq    = (const float*)d_in[5];
    const float*   Wkv   = (const float*)d_in[6];
    const float*   Wout  = (const float*)d_in[7];
    float* out = (float*)d_out;

    char* ws = (char*)d_ws;
    const size_t MB = 1u << 20;
    int*      qt    = (int*)(ws);                  // 32 KB
    unsigned* cnt   = (unsigned*)(ws + (64 << 10)); // barrier counter
    u16* Aq    = (u16*)(ws + 1  * MB);        // [1,17) MB  (dead after proj)
    u16* aob   = (u16*)(ws + 1  * MB);        // [1,9)  MB  (reuses Aq region)
    u16* Akv   = (u16*)(ws + 17 * MB);        // [17,25) MB
    u16* Wqt   = (u16*)(ws + 25 * MB);        // 1 MB
    u16* Wkvt  = (u16*)(ws + 26 * MB);        // 2 MB
    u16* Woutt = (u16*)(ws + 28 * MB);        // 1 MB
    u16* qb    = (u16*)(ws + 29 * MB);        // [29,37) MB
    u16* kvb   = (u16*)(ws + 37 * MB);        // [37,45) MB

    prep_k<<<dim3(12292), dim3(256), 0, stream>>>(qo, kvo, media, ln_g, ln_b,
                                                  Wq, Wkv, Wout,
                                                  qt, Aq, Akv, Wqt, Wkvt, Woutt, cnt);
    mega_k<<<dim3(512), dim3(256), 0, stream>>>(Aq, Wqt, qb, Akv, Wkvt, kvb,
                                                qt, aob, Woutt, out, cnt);
}

// Round 8
// 166.909 us; speedup vs baseline: 1.8266x; 1.8266x over previous
//
#include <hip/hip_runtime.h>
#include <cstdint>
#include <cstddef>

// Problem constants (MaskedCrossAttention_27986006901343)
#define BB    4
#define TQ    2048
#define DIM   1024
#define TKV   16
#define NLAT  64
#define DLAT  1024
#define HEADS 8
#define DHEAD 64
#define LN_EPS 1e-5f
#define NKV   (TKV*NLAT)      // 1024 latents per batch
#define HD    (HEADS*DHEAD)   // 512

typedef unsigned short u16;
typedef __bf16 bf16x8 __attribute__((ext_vector_type(8)));
typedef float  f32x4  __attribute__((ext_vector_type(4)));

__device__ __forceinline__ u16 f2bf(float f) {      // RNE f32->bf16
    unsigned u = __builtin_bit_cast(unsigned, f);
    u += 0x7fffu + ((u >> 16) & 1u);
    return (u16)(u >> 16);
}
__device__ __forceinline__ void gl_lds16(const void* g, void* l) {
    __builtin_amdgcn_global_load_lds(
        (const __attribute__((address_space(1))) void*)g,
        (__attribute__((address_space(3))) void*)l, 16, 0, 0);
}
// Swizzled element index: within each 64-elem group, 8-elem chunk c -> c^(row&7).
// Applied at PRODUCTION of every gl_lds-consumed array (rule 21 both-sides):
// gl_lds then copies linearly, and the GEMM fragment read applies the same XOR
// -> conflict-free ds_read_b128 (2 lanes/bank, free per m136).
__device__ __forceinline__ int swz_idx(int col, int row) {
    return (col & ~63) | ((((col >> 3) & 7) ^ (row & 7)) << 3) | (col & 7);
}

// ===========================================================================
// prep_k: qtime + LN(qo)->bf16(swz) + cvt(kvo)->bf16(swz) + 3 W^T packs (swz).
// ===========================================================================
__device__ __forceinline__ void transpose_dev(const float* __restrict__ W,
                                              u16* __restrict__ Wt,
                                              int K, int N, int n0, int k0,
                                              float (*tile)[33]) {
    int t = threadIdx.x;
    int r = t >> 3, c4 = (t & 7) * 4;
    float4 v = *(const float4*)&W[(size_t)(k0 + r) * N + n0 + c4];
    tile[r][c4 + 0] = v.x; tile[r][c4 + 1] = v.y;
    tile[r][c4 + 2] = v.z; tile[r][c4 + 3] = v.w;
    __syncthreads();
    uint2 pk;
    pk.x = (unsigned)f2bf(tile[c4 + 0][r]) | ((unsigned)f2bf(tile[c4 + 1][r]) << 16);
    pk.y = (unsigned)f2bf(tile[c4 + 2][r]) | ((unsigned)f2bf(tile[c4 + 3][r]) << 16);
    int n = n0 + r, k = k0 + c4;
    *(uint2*)&Wt[(size_t)n * K + swz_idx(k, n)] = pk;
}

__global__ __launch_bounds__(256) void prep_k(
    const float* __restrict__ qo, const float* __restrict__ kvo,
    const uint8_t* __restrict__ media,
    const float* __restrict__ ln_g, const float* __restrict__ ln_b,
    const float* __restrict__ Wq, const float* __restrict__ Wkv,
    const float* __restrict__ Wout,
    int* __restrict__ qt, u16* __restrict__ Aq, u16* __restrict__ Akv,
    u16* __restrict__ Wqt, u16* __restrict__ Wkvt, u16* __restrict__ Woutt) {
    __shared__ int part[256];
    __shared__ int cnt_sh;
    __shared__ float sh[8];
    __shared__ float mu_s, rs_s;
    __shared__ float tile[32][33];
    int blk = blockIdx.x, t = threadIdx.x;

    if (blk < 4) {                    // ---- qtime (media dtype sniffed) ----
        int b = blk;
        int c = 0;
        for (int i = 0; i < 32; ++i) c += (media[t * 32 + i] != 0);
        part[t] = c;
        __syncthreads();
        if (t == 0) { int s = 0; for (int i = 0; i < 256; ++i) s += part[i]; cnt_sh = s; }
        __syncthreads();
        bool is_u8 = (cnt_sh >= 48);
        int vals[8];
        for (int i = 0; i < 8; ++i) {
            int idx = t * 8 + i;
            int m;
            if (is_u8) m = (media[(size_t)b * TQ + idx] != 0) ? 1 : 0;
            else       m = (((const uint32_t*)media)[(size_t)b * TQ + idx] != 0u) ? 1 : 0;
            vals[i] = m;
        }
        int loc = 0;
        for (int i = 0; i < 8; ++i) loc += vals[i];
        __syncthreads();
        part[t] = loc;
        __syncthreads();
        int pre = 0;
        for (int i = 0; i < t; ++i) pre += part[i];
        int run = pre;
        for (int i = 0; i < 8; ++i) {
            run += vals[i];
            qt[(size_t)b * TQ + t * 8 + i] = run;
        }
    } else if (blk < 4 + BB * TQ) {   // ---- LayerNorm + bf16 (swizzled) ----
        int row = blk - 4;
        float4 v = *(const float4*)(qo + (size_t)row * DIM + t * 4);
        float s  = v.x + v.y + v.z + v.w;
        float ss = v.x * v.x + v.y * v.y + v.z * v.z + v.w * v.w;
        for (int off = 32; off; off >>= 1) { s += __shfl_down(s, off); ss += __shfl_down(ss, off); }
        if ((t & 63) == 0) { sh[(t >> 6) * 2] = s; sh[(t >> 6) * 2 + 1] = ss; }
        __syncthreads();
        if (t == 0) {
            float S  = sh[0] + sh[2] + sh[4] + sh[6];
            float SS = sh[1] + sh[3] + sh[5] + sh[7];
            float m  = S * (1.0f / DIM);
            mu_s = m;
            rs_s = rsqrtf(SS * (1.0f / DIM) - m * m + LN_EPS);
        }
        __syncthreads();
        float mu = mu_s, rs = rs_s;
        float4 gv = *(const float4*)(ln_g + t * 4);
        float4 bv = *(const float4*)(ln_b + t * 4);
        float a0 = (v.x - mu) * rs * gv.x + bv.x;
        float a1 = (v.y - mu) * rs * gv.y + bv.y;
        float a2 = (v.z - mu) * rs * gv.z + bv.z;
        float a3 = (v.w - mu) * rs * gv.w + bv.w;
        uint2 pk;
        pk.x = (unsigned)f2bf(a0) | ((unsigned)f2bf(a1) << 16);
        pk.y = (unsigned)f2bf(a2) | ((unsigned)f2bf(a3) << 16);
        *(uint2*)(Aq + (size_t)row * DIM + swz_idx(t * 4, row)) = pk;
    } else if (blk < 4 + BB * TQ + 2048) {   // ---- kvo f32->bf16 (swizzled) ----
        size_t i = (size_t)(blk - 4 - BB * TQ) * 256 + t;   // 16B-chunk index
        float4 a = ((const float4*)kvo)[i * 2];
        float4 b = ((const float4*)kvo)[i * 2 + 1];
        uint4 pk;
        pk.x = (unsigned)f2bf(a.x) | ((unsigned)f2bf(a.y) << 16);
        pk.y = (unsigned)f2bf(a.z) | ((unsigned)f2bf(a.w) << 16);
        pk.z = (unsigned)f2bf(b.x) | ((unsigned)f2bf(b.y) << 16);
        pk.w = (unsigned)f2bf(b.z) | ((unsigned)f2bf(b.w) << 16);
        int row = (int)(i >> 7);              // 128 chunks per 1024-elem row
        size_t di = (i & ~(size_t)7) | (size_t)(((int)i & 7) ^ (row & 7));
        ((uint4*)Akv)[di] = pk;
    } else if (blk < 10244 + 512) {   // ---- Wq^T (swz) ----
        int id = blk - 10244;
        transpose_dev(Wq, Wqt, DIM, HD, (id & 15) * 32, (id >> 4) * 32, tile);
    } else if (blk < 10756 + 1024) {  // ---- Wkv^T (swz) ----
        int id = blk - 10756;
        transpose_dev(Wkv, Wkvt, DLAT, 2 * HD, (id & 31) * 32, (id >> 5) * 32, tile);
    } else {                          // ---- Wout^T (swz) ----
        int id = blk - 11780;
        transpose_dev(Wout, Woutt, HD, DIM, (id & 31) * 32, (id >> 5) * 32, tile);
    }
}

// ===========================================================================
// bf16 MFMA GEMM: C = A @ Bt^T * outscale.  128x128 tile, BK=64, 4 waves,
// 2-phase double buffer, gl_lds staging from PRE-SWIZZLED globals,
// XOR fragment reads -> conflict-free ds_read_b128. LDS 4x16KB = 64KB.
// Half the barriers of BK=32 (16/8 K-steps at K=1024/512).
// ===========================================================================
template <typename CT>
__device__ __forceinline__ void gemm_body(const u16* A, const u16* Bt, CT* C,
                                          int M, int N, int K, float outscale,
                                          int bx, int by,
                                          u16* As0, u16* Bs0, u16* As1, u16* Bs1) {
    int t = threadIdx.x;
    int lane = t & 63, w = t >> 6;
    int wr = w >> 1, wc = w & 1;
    int fr = lane & 15, fg = lane >> 4;
    int row0 = by * 128, col0 = bx * 128;
    int swz = fr & 7;

    // staging: wave w, instr q covers LDS rows w*32+q*8+(lane>>3), chunk lane&7
    const u16* Ag = A  + (size_t)(row0 + w * 32 + (lane >> 3)) * K + (lane & 7) * 8;
    const u16* Bg = Bt + (size_t)(col0 + w * 32 + (lane >> 3)) * K + (lane & 7) * 8;
    size_t i8K = (size_t)8 * K;

    f32x4 acc[4][4];
#pragma unroll
    for (int mi = 0; mi < 4; ++mi)
#pragma unroll
        for (int ni = 0; ni < 4; ++ni) acc[mi][ni] = (f32x4){0.f, 0.f, 0.f, 0.f};

    auto stage = [&](u16* Asb, u16* Bsb, int kt) {
        int k0 = kt << 6;
#pragma unroll
        for (int q = 0; q < 4; ++q) {
            gl_lds16(Ag + k0 + q * i8K, (char*)Asb + w * 4096 + q * 1024);
            gl_lds16(Bg + k0 + q * i8K, (char*)Bsb + w * 4096 + q * 1024);
        }
    };
    auto compute = [&](const u16* Asb, const u16* Bsb) {
#pragma unroll
        for (int ks = 0; ks < 2; ++ks) {
            bf16x8 af[4], bfv[4];
#pragma unroll
            for (int mi = 0; mi < 4; ++mi)
                af[mi] = *(const bf16x8*)((const char*)Asb +
                    (wr * 64 + mi * 16 + fr) * 128 + (((ks * 4 + fg) ^ swz) << 4));
#pragma unroll
            for (int ni = 0; ni < 4; ++ni)
                bfv[ni] = *(const bf16x8*)((const char*)Bsb +
                    (wc * 64 + ni * 16 + fr) * 128 + (((ks * 4 + fg) ^ swz) << 4));
#pragma unroll
            for (int mi = 0; mi < 4; ++mi)
#pragma unroll
                for (int ni = 0; ni < 4; ++ni)
                    acc[mi][ni] = __builtin_amdgcn_mfma_f32_16x16x32_bf16(
                        af[mi], bfv[ni], acc[mi][ni], 0, 0, 0);
        }
    };

    int nt = K >> 6;                 // 16 or 8 (even)
    stage(As0, Bs0, 0);
    __syncthreads();
    for (int kt = 0; kt < nt; kt += 2) {
        stage(As1, Bs1, kt + 1);
        compute(As0, Bs0);
        __syncthreads();
        if (kt + 2 < nt) stage(As0, Bs0, kt + 2);
        compute(As1, Bs1);
        __syncthreads();
    }

#pragma unroll
    for (int mi = 0; mi < 4; ++mi) {
        int r0 = row0 + wr * 64 + mi * 16 + fg * 4;
#pragma unroll
        for (int ni = 0; ni < 4; ++ni) {
            int c = col0 + wc * 64 + ni * 16 + fr;
#pragma unroll
            for (int j = 0; j < 4; ++j) {
                float val = acc[mi][ni][j] * outscale;
                if constexpr (sizeof(CT) == 2) C[(size_t)(r0 + j) * N + c] = f2bf(val);
                else                           C[(size_t)(r0 + j) * N + c] = val;
            }
        }
    }
}

// Fused q-proj + kv-proj: 512 blocks (2/CU). qb/kvb written LINEAR
// (consumed by attn via register loads, not gl_lds).
__global__ __launch_bounds__(256) void proj_k(
    const u16* __restrict__ Aq,  const u16* __restrict__ Wqt,  u16* __restrict__ qb,
    const u16* __restrict__ Akv, const u16* __restrict__ Wkvt, u16* __restrict__ kvb) {
    __shared__ u16 As0[8192], Bs0[8192], As1[8192], Bs1[8192];   // 64KB
    int id = blockIdx.x;
    if (id < 256) {   // q-proj: M=8192 (by<64), N=512 (bx<4)
        gemm_body<u16>(Aq, Wqt, qb, BB * TQ, HD, DIM, 0.125f, id & 3, id >> 2,
                       As0, Bs0, As1, Bs1);
    } else {          // kv-proj: M=4096 (by<32), N=1024 (bx<8)
        id -= 256;
        gemm_body<u16>(Akv, Wkvt, kvb, BB * NKV, 2 * HD, DLAT, 1.0f, id & 7, id >> 3,
                       As0, Bs0, As1, Bs1);
    }
}

// out-proj: M=8192 (by<64), N=1024 (bx<8) -> 512 blocks. A = swizzled aob.
__global__ __launch_bounds__(256) void out_k(
    const u16* __restrict__ aob, const u16* __restrict__ Woutt, float* __restrict__ out) {
    __shared__ u16 As0[8192], Bs0[8192], As1[8192], Bs1[8192];
    int id = blockIdx.x;
    gemm_body<float>(aob, Woutt, out, BB * TQ, DIM, HD, 1.0f, id & 7, id >> 3,
                     As0, Bs0, As1, Bs1);
}

// ===========================================================================
// MFMA masked cross attention (R3-proven math). Reads qb/kvb LINEAR;
// writes aob PRE-SWIZZLED (it feeds out_k's gl_lds staging).
// ===========================================================================
__global__ __launch_bounds__(256) void attn_k(
    const u16* __restrict__ q,    // (B*TQ, 512) bf16, pre-scaled by 0.125
    const u16* __restrict__ kv,   // (B*NKV, 1024) bf16: k [0,512), v [512,1024)
    const int* __restrict__ qt,
    u16* __restrict__ ao) {       // (B*TQ, 512) bf16, swizzled layout
    __shared__ u16 Ks[4096];      // swizzled [64][64]
    __shared__ u16 VT[4096];      // swizzled [64 d][64 lat]
    __shared__ u16 Ps[1024];      // swizzled [16][64]
    __shared__ float redm[4][16], reds[4][16];
    int i0 = blockIdx.x * 16;
    int h  = blockIdx.y;
    int b  = blockIdx.z;
    int t  = threadIdx.x;
    int lane = t & 63, w = t >> 6;
    int fr = lane & 15, fg = lane >> 4;

    int t0 = qt[(size_t)b * TQ + i0];
    if (t0 == 0) {
        int row = i0 + (t >> 4), cc = h * DHEAD + (t & 15) * 4;
        *(uint2*)&ao[((size_t)(b * TQ + row)) * HD + swz_idx(cc, row)] = make_uint2(0, 0);
        return;
    }
    int j0 = (t0 - 1) * 64;

    {   // stage K (swizzled row-major) + V (transposed, swizzled) -- LDS-local swizzle
        int j = t >> 2, c16 = (t & 3) * 16;
        const u16* kvrow = kv + ((size_t)(b * NKV + j0 + j)) * (2 * HD) + h * DHEAD;
        uint4 k0v = *(const uint4*)(kvrow + c16);
        uint4 k1v = *(const uint4*)(kvrow + c16 + 8);
        uint4 v0v = *(const uint4*)(kvrow + HD + c16);
        uint4 v1v = *(const uint4*)(kvrow + HD + c16 + 8);
        int kb = j * 128 + c16 * 2;
        int sw = (j & 7) << 4;
        *(uint4*)((char*)Ks + ((kb)      ^ sw)) = k0v;
        *(uint4*)((char*)Ks + ((kb + 16) ^ sw)) = k1v;
        const u16* ve0 = (const u16*)&v0v;
        const u16* ve1 = (const u16*)&v1v;
#pragma unroll
        for (int e = 0; e < 8; ++e) {
            int d0 = c16 + e, d1 = c16 + 8 + e;
            *(u16*)((char*)VT + ((d0 * 128 + j * 2) ^ ((d0 & 7) << 4))) = ve0[e];
            *(u16*)((char*)VT + ((d1 * 128 + j * 2) ^ ((d1 & 7) << 4))) = ve1[e];
        }
    }
    const u16* qrow = q + ((size_t)(b * TQ + i0 + fr)) * HD + h * DHEAD + fg * 8;
    bf16x8 aq0 = *(const bf16x8*)(qrow);
    bf16x8 aq1 = *(const bf16x8*)(qrow + 32);
    __syncthreads();

    // QK^T: wave w computes S[16][w*16..w*16+16)
    int r = w * 16 + fr;
    bf16x8 bk0 = *(const bf16x8*)((char*)Ks + ((r * 128 + fg * 16)      ^ ((r & 7) << 4)));
    bf16x8 bk1 = *(const bf16x8*)((char*)Ks + ((r * 128 + 64 + fg * 16) ^ ((r & 7) << 4)));
    f32x4 s = (f32x4){0.f, 0.f, 0.f, 0.f};
    s = __builtin_amdgcn_mfma_f32_16x16x32_bf16(aq0, bk0, s, 0, 0, 0);
    s = __builtin_amdgcn_mfma_f32_16x16x32_bf16(aq1, bk1, s, 0, 0, 0);

    // softmax over 64 cols (4 waves x 16)
#pragma unroll
    for (int j = 0; j < 4; ++j) {
        float m = s[j];
        for (int off = 1; off < 16; off <<= 1) m = fmaxf(m, __shfl_xor(m, off));
        redm[w][fg * 4 + j] = m;
    }
    __syncthreads();
    float p[4];
#pragma unroll
    for (int j = 0; j < 4; ++j) {
        int row = fg * 4 + j;
        float M = fmaxf(fmaxf(redm[0][row], redm[1][row]), fmaxf(redm[2][row], redm[3][row]));
        p[j] = __expf(s[j] - M);
        float sm = p[j];
        for (int off = 1; off < 16; off <<= 1) sm += __shfl_xor(sm, off);
        reds[w][row] = sm;
    }
    __syncthreads();
#pragma unroll
    for (int j = 0; j < 4; ++j) {
        int row = fg * 4 + j;
        float S = reds[0][row] + reds[1][row] + reds[2][row] + reds[3][row];
        u16 pb = f2bf(p[j] / S);
        *(u16*)((char*)Ps + ((row * 128 + (w * 16 + fr) * 2) ^ ((row & 7) << 4))) = pb;
    }
    __syncthreads();

    // PV: wave w computes O[16][w*16..w*16+16)
    bf16x8 pa0 = *(const bf16x8*)((char*)Ps + ((fr * 128 + fg * 16)      ^ ((fr & 7) << 4)));
    bf16x8 pa1 = *(const bf16x8*)((char*)Ps + ((fr * 128 + 64 + fg * 16) ^ ((fr & 7) << 4)));
    int d = w * 16 + fr;
    bf16x8 bv0 = *(const bf16x8*)((char*)VT + ((d * 128 + fg * 16)      ^ ((d & 7) << 4)));
    bf16x8 bv1 = *(const bf16x8*)((char*)VT + ((d * 128 + 64 + fg * 16) ^ ((d & 7) << 4)));
    f32x4 o = (f32x4){0.f, 0.f, 0.f, 0.f};
    o = __builtin_amdgcn_mfma_f32_16x16x32_bf16(pa0, bv0, o, 0, 0, 0);
    o = __builtin_amdgcn_mfma_f32_16x16x32_bf16(pa1, bv1, o, 0, 0, 0);
    int cc = h * DHEAD + d;
#pragma unroll
    for (int j = 0; j < 4; ++j) {
        int row = i0 + fg * 4 + j;
        ao[((size_t)(b * TQ + row)) * HD + swz_idx(cc, row)] = f2bf(o[j]);
    }
}

// ===========================================================================
extern "C" void kernel_launch(void* const* d_in, const int* in_sizes, int n_in,
                              void* d_out, int out_size, void* d_ws, size_t ws_size,
                              hipStream_t stream) {
    const float*   qo    = (const float*)d_in[0];
    const float*   kvo   = (const float*)d_in[1];
    const uint8_t* media = (const uint8_t*)d_in[2];
    const float*   ln_g  = (const float*)d_in[3];
    const float*   ln_b  = (const float*)d_in[4];
    const float*   Wq    = (const float*)d_in[5];
    const float*   Wkv   = (const float*)d_in[6];
    const float*   Wout  = (const float*)d_in[7];
    float* out = (float*)d_out;

    char* ws = (char*)d_ws;
    const size_t MB = 1u << 20;
    int* qt    = (int*)(ws);                  // 32 KB
    u16* Aq    = (u16*)(ws + 1  * MB);        // [1,17) MB  swz LN'd qo (dead after proj)
    u16* aob   = (u16*)(ws + 1  * MB);        // [1,9)  MB  swz attn out (reuses Aq region)
    u16* Akv   = (u16*)(ws + 17 * MB);        // [17,25) MB swz kvo bf16
    u16* Wqt   = (u16*)(ws + 25 * MB);        // 1 MB  swz
    u16* Wkvt  = (u16*)(ws + 26 * MB);        // 2 MB  swz
    u16* Woutt = (u16*)(ws + 28 * MB);        // 1 MB  swz
    u16* qb    = (u16*)(ws + 29 * MB);        // [29,37) MB linear
    u16* kvb   = (u16*)(ws + 37 * MB);        // [37,45) MB linear

    prep_k<<<dim3(12292), dim3(256), 0, stream>>>(qo, kvo, media, ln_g, ln_b,
                                                  Wq, Wkv, Wout,
                                                  qt, Aq, Akv, Wqt, Wkvt, Woutt);
    proj_k<<<dim3(512), dim3(256), 0, stream>>>(Aq, Wqt, qb, Akv, Wkvt, kvb);
    attn_k<<<dim3(TQ / 16, HEADS, BB), dim3(256), 0, stream>>>(qb, kvb, qt, aob);
    out_k<<<dim3(512), dim3(256), 0, stream>>>(aob, Woutt, out);
}